// Round 3
// baseline (224.408 us; speedup 1.0000x reference)
//
#include <hip/hip_runtime.h>
#include <hip/hip_bf16.h>

typedef __attribute__((ext_vector_type(8))) short  short8;
typedef __attribute__((ext_vector_type(4))) float  f32x4;
typedef __attribute__((ext_vector_type(4))) ushort u16x4;

#define MFMA16(a, b, c) __builtin_amdgcn_mfma_f32_16x16x32_bf16((a), (b), (c), 0, 0, 0)

static constexpr int S    = 4096;
static constexpr int H    = 16;
static constexpr int D    = 64;
static constexpr int HS   = H * D;    // 1024 f32 per seq position
static constexpr int KVT  = 64;       // keys per block-iteration
static constexpr int QBLK = 128;      // q rows per block (8 waves x 16)
static constexpr int NW   = 8;        // waves per block
static constexpr int PST  = 72;       // padded LDS row stride (elems); 144 B, 16B-aligned

// RNE float -> bf16 bits (finite inputs only)
__device__ __forceinline__ ushort f2bf(float x) {
  union { float f; unsigned u; } a; a.f = x;
  unsigned r = a.u + 0x7fffu + ((a.u >> 16) & 1u);
  return (ushort)(r >> 16);
}

// Pre-pass: K,V f32 [S][H][D] -> bf16 [H][S][D] in workspace
__global__ __launch_bounds__(256) void cast_hd(
    const float* __restrict__ Kf, const float* __restrict__ Vf,
    ushort* __restrict__ Kb, ushort* __restrict__ Vb)
{
  const int e = (blockIdx.x * 256 + threadIdx.x) * 4;  // flat OUTPUT idx [h][s][d]
  const int d = e & 63;
  const int s = (e >> 6) & (S - 1);
  const int h = e >> 18;
  const size_t in_off = (size_t)s * HS + h * D + d;
  f32x4 kv = *(const f32x4*)(Kf + in_off);
  f32x4 vv = *(const f32x4*)(Vf + in_off);
  u16x4 kb, vb;
  #pragma unroll
  for (int j = 0; j < 4; ++j) { kb[j] = f2bf(kv[j]); vb[j] = f2bf(vv[j]); }
  *(u16x4*)(Kb + e) = kb;
  *(u16x4*)(Vb + e) = vb;
}

__device__ __forceinline__ short8 pack8(f32x4 a, f32x4 b, float scl) {
  short8 r;
  #pragma unroll
  for (int j = 0; j < 4; ++j) {
    r[j]     = (short)f2bf(a[j] * scl);
    r[4 + j] = (short)f2bf(b[j] * scl);
  }
  return r;
}

template<bool PRE>
__global__ __launch_bounds__(512) void attn_fwd(
    const float*  __restrict__ Q,  const float*  __restrict__ Kf,
    const float*  __restrict__ Vf, const ushort* __restrict__ Kb,
    const ushort* __restrict__ Vb, float* __restrict__ O)
{
  __shared__ __align__(16) ushort Klds[KVT][PST];    // [key][d]
  __shared__ __align__(16) ushort Vt[D][PST];        // [d][key]  (transposed V)
  __shared__ __align__(16) ushort Plds[NW][16][PST]; // per-wave [q][key]

  const int tid  = threadIdx.x;
  const int wid  = tid >> 6;
  const int lane = tid & 63;
  const int g    = lane >> 4;   // 16-lane group 0..3
  const int ln   = lane & 15;
  const int h    = blockIdx.y;
  const int q0   = blockIdx.x * QBLK + wid * 16;

  const float SCL = 0.125f * 1.4426950408889634f;  // softmax scale * log2(e), folded into Q

  // Q fragments (B-operand of swapped QK^T): lane holds Q[q0+ln][g*8..+7] and [32+g*8..+7]
  short8 qf[2];
  {
    const float* qp = Q + (size_t)(q0 + ln) * HS + h * D + g * 8;
    f32x4 a0 = *(const f32x4*)(qp);
    f32x4 a1 = *(const f32x4*)(qp + 4);
    f32x4 a2 = *(const f32x4*)(qp + 32);
    f32x4 a3 = *(const f32x4*)(qp + 36);
    qf[0] = pack8(a0, a1, SCL);
    qf[1] = pack8(a2, a3, SCL);
  }

  // NOTE on lane spaces (the round-2 bug):
  //  - softmax stats (m_run, l_run, alpha) live in "row q = ln" space (QK^T C/D col)
  //  - oacc[dt][r] lives in "row q = 4g+r" space (PV C/D row)
  //  alpha must be shfl'd from lane 4g+r before rescaling oacc.
  float m_run = -1e30f, l_run = 0.0f;
  f32x4 oacc[4] = {};   // lane holds O[q=4g+r][d=dt*16+ln]

  const size_t hb = (size_t)h * S * D;  // bf16 head base for [H][S][D]

  for (int t = 0; t < S / KVT; ++t) {
    const int kv0 = t * KVT;

    // ---- stage K (row-major bf16) + V (transposed) ----
    if constexpr (PRE) {
      const int key = tid >> 3;          // 0..63
      const int d0  = (tid & 7) * 8;     // 0..56
      short8 kv = *(const short8*)(Kb + hb + (size_t)(kv0 + key) * D + d0);
      *(short8*)&Klds[key][d0] = kv;
      short8 vv = *(const short8*)(Vb + hb + (size_t)(kv0 + key) * D + d0);
      #pragma unroll
      for (int j = 0; j < 8; ++j) Vt[d0 + j][key] = (ushort)vv[j];
    } else {
      #pragma unroll
      for (int r = 0; r < 2; ++r) {
        const int key = r * 32 + (tid >> 4);
        const int d0  = (tid & 15) * 4;
        f32x4 kq = *(const f32x4*)(Kf + (size_t)(kv0 + key) * HS + h * D + d0);
        u16x4 kb4;
        #pragma unroll
        for (int j = 0; j < 4; ++j) kb4[j] = f2bf(kq[j]);
        *(u16x4*)&Klds[key][d0] = kb4;
        f32x4 vq = *(const f32x4*)(Vf + (size_t)(kv0 + key) * HS + h * D + d0);
        #pragma unroll
        for (int j = 0; j < 4; ++j) Vt[d0 + j][key] = f2bf(vq[j]);
      }
    }
    __syncthreads();

    // ---- QK^T (swapped: mfma(K, Q) -> S^T): sv[kt][r] = z[q=ln][key=kt*16+4g+r] ----
    f32x4 sv[4];
    #pragma unroll
    for (int kt = 0; kt < 4; ++kt) {
      f32x4 acc = {};
      short8 kf0 = *(const short8*)&Klds[kt * 16 + ln][g * 8];
      short8 kf1 = *(const short8*)&Klds[kt * 16 + ln][32 + g * 8];
      acc = MFMA16(kf0, qf[0], acc);
      acc = MFMA16(kf1, qf[1], acc);
      sv[kt] = acc;
    }

    // ---- online softmax (exp2 domain; scale already folded into Q) ----
    float zmax = -1e30f;
    #pragma unroll
    for (int kt = 0; kt < 4; ++kt)
      #pragma unroll
      for (int r = 0; r < 4; ++r) zmax = fmaxf(zmax, sv[kt][r]);
    zmax = fmaxf(zmax, __shfl_xor(zmax, 16));
    zmax = fmaxf(zmax, __shfl_xor(zmax, 32));
    const float m_new = fmaxf(m_run, zmax);
    const float alpha = __builtin_amdgcn_exp2f(m_run - m_new);   // for row q = ln

    float psum = 0.0f;
    #pragma unroll
    for (int kt = 0; kt < 4; ++kt) {
      float p[4];
      #pragma unroll
      for (int r = 0; r < 4; ++r) {
        p[r] = __builtin_amdgcn_exp2f(sv[kt][r] - m_new);
        psum += p[r];
      }
      unsigned w0 = (unsigned)f2bf(p[0]) | ((unsigned)f2bf(p[1]) << 16);
      unsigned w1 = (unsigned)f2bf(p[2]) | ((unsigned)f2bf(p[3]) << 16);
      unsigned* dst = (unsigned*)&Plds[wid][ln][kt * 16 + g * 4];
      dst[0] = w0; dst[1] = w1;
    }
    psum += __shfl_xor(psum, 16);
    psum += __shfl_xor(psum, 32);
    l_run = l_run * alpha + psum;
    m_run = m_new;

    // FIX: rescale oacc with the alpha of ITS row (q = 4g+r), not row ln.
    // Lane 4g+r has ln == 4g+r, so it holds alpha for row q = 4g+r.
    #pragma unroll
    for (int r = 0; r < 4; ++r) {
      const float a_q = __shfl(alpha, 4 * g + r);
      #pragma unroll
      for (int dt = 0; dt < 4; ++dt) oacc[dt][r] *= a_q;
    }
    __syncthreads();   // P visible wave-wide

    // ---- PV: O[q][d] += P[q][k] * V[k][d] ----
    short8 pa0 = *(const short8*)&Plds[wid][ln][g * 8];
    short8 pa1 = *(const short8*)&Plds[wid][ln][32 + g * 8];
    #pragma unroll
    for (int dt = 0; dt < 4; ++dt) {
      short8 vb0 = *(const short8*)&Vt[dt * 16 + ln][g * 8];
      short8 vb1 = *(const short8*)&Vt[dt * 16 + ln][32 + g * 8];
      oacc[dt] = MFMA16(pa0, vb0, oacc[dt]);
      oacc[dt] = MFMA16(pa1, vb1, oacc[dt]);
    }
    __syncthreads();   // protect Klds/Vt before next stage
  }

  // ---- epilogue: divide by row sum, store f32 ----
  #pragma unroll
  for (int r = 0; r < 4; ++r) {
    const int q = 4 * g + r;
    const float lv  = __shfl(l_run, q);   // lane q holds row-q sum (ln==q)
    const float inv = 1.0f / lv;
    float* op = O + (size_t)(q0 + q) * HS + h * D + ln;
    #pragma unroll
    for (int dt = 0; dt < 4; ++dt)
      op[dt * 16] = oacc[dt][r] * inv;
  }
}

extern "C" void kernel_launch(void* const* d_in, const int* in_sizes, int n_in,
                              void* d_out, int out_size, void* d_ws, size_t ws_size,
                              hipStream_t stream) {
  const float* Q = (const float*)d_in[0];
  const float* K = (const float*)d_in[1];
  const float* V = (const float*)d_in[2];
  float* O = (float*)d_out;

  const size_t elems = (size_t)H * S * D;             // 4M per tensor
  const size_t need  = 2 * elems * sizeof(ushort);    // 16 MB bf16 K+V

  dim3 grid(S / QBLK, H);  // (32, 16)
  if (ws_size >= need) {
    ushort* Kb = (ushort*)d_ws;
    ushort* Vb = Kb + elems;
    cast_hd<<<dim3((unsigned)(elems / (256 * 4))), 256, 0, stream>>>(K, V, Kb, Vb);
    attn_fwd<true><<<grid, dim3(512), 0, stream>>>(Q, K, V, Kb, Vb, O);
  } else {
    attn_fwd<false><<<grid, dim3(512), 0, stream>>>(Q, K, V, nullptr, nullptr, O);
  }
}

// Round 4
// 154.978 us; speedup vs baseline: 1.4480x; 1.4480x over previous
//
#include <hip/hip_runtime.h>
#include <hip/hip_bf16.h>

typedef __attribute__((ext_vector_type(8))) short  short8;
typedef __attribute__((ext_vector_type(4))) float  f32x4;
typedef __attribute__((ext_vector_type(4))) ushort u16x4;

#define MFMA16(a,b,c) __builtin_amdgcn_mfma_f32_16x16x32_bf16((a),(b),(c),0,0,0)

static constexpr int S   = 4096;
static constexpr int H   = 16;
static constexpr int D   = 64;
static constexpr int HS  = H * D;     // 1024 f32 per seq position
static constexpr int NT  = S / 64;    // 64 KV tiles of 64 keys
static constexpr int TILE_BYTES = 16384;  // 8KB K-image + 8KB V-image

// RNE float -> bf16 bits (finite inputs only)
__device__ __forceinline__ ushort f2bf(float x) {
  union { float f; unsigned u; } a; a.f = x;
  unsigned r = a.u + 0x7fffu + ((a.u >> 16) & 1u);
  return (ushort)(r >> 16);
}

__device__ __forceinline__ short8 pack8(f32x4 a, f32x4 b, float scl) {
  short8 r;
  #pragma unroll
  for (int j = 0; j < 4; ++j) {
    r[j]     = (short)f2bf(a[j] * scl);
    r[4 + j] = (short)f2bf(b[j] * scl);
  }
  return r;
}

// async global->LDS, 16B per lane; LDS dest is wave-uniform base + lane*16
__device__ __forceinline__ void gload16(const void* g, void* l) {
  __builtin_amdgcn_global_load_lds(
      (const __attribute__((address_space(1))) unsigned int*)g,
      (__attribute__((address_space(3))) unsigned int*)l, 16, 0, 0);
}

// ---------------------------------------------------------------------------
// Pre-pass: build per-(h,t) 16KB LDS images in workspace.
//   K-image byte X = (key*128 + d*2) ^ ((key&7)<<4)   holds bf16 K[t*64+key][h][d]
//   V-image byte X = (d*128 + k*2)  ^ ((d&7)<<4)      holds bf16 V[t*64+k][h][d]
// Swizzle baked here so the main kernel stages with LINEAR global_load_lds and
// reads with the same XOR (rule #21: pre-swizzled source + swizzled read).
// ---------------------------------------------------------------------------
__global__ __launch_bounds__(256) void build_imgs(
    const float* __restrict__ Kf, const float* __restrict__ Vf,
    char* __restrict__ ws)
{
  __shared__ float vt[64][65];   // f32 V tile, padded for transposed reads
  const int tid = threadIdx.x;
  const int t   = blockIdx.x;
  const int h   = blockIdx.y;
  const size_t base_in = (size_t)(t * 64) * HS + h * D;

  #pragma unroll
  for (int i = 0; i < 4; ++i) {           // stage V tile [64 key][64 d] f32
    const int idx = i * 256 + tid;
    const int key = idx >> 4;
    const int c4  = (idx & 15) * 4;
    f32x4 v = *(const f32x4*)(Vf + base_in + (size_t)key * HS + c4);
    *(f32x4*)&vt[key][c4] = v;
  }
  __syncthreads();

  char* Kimg = ws + (size_t)(h * NT + t) * TILE_BYTES;
  char* Vimg = Kimg + 8192;

  #pragma unroll
  for (int i = 0; i < 2; ++i) {
    const int c   = i * 256 + tid;        // chunk id 0..511
    const int key = c >> 3;
    const int d0  = (c & 7) * 8;
    // K: straight cast, swizzled placement
    f32x4 a = *(const f32x4*)(Kf + base_in + (size_t)key * HS + d0);
    f32x4 b = *(const f32x4*)(Kf + base_in + (size_t)key * HS + d0 + 4);
    short8 kb = pack8(a, b, 1.0f);
    *(short8*)(Kimg + ((key * 128 + d0 * 2) ^ ((key & 7) << 4))) = kb;
    // V: transposed row d=key-slot, keys k0..k0+7
    const int dd = c >> 3;
    const int k0 = (c & 7) * 8;
    short8 vb;
    #pragma unroll
    for (int j = 0; j < 8; ++j) vb[j] = (short)f2bf(vt[k0 + j][dd]);
    *(short8*)(Vimg + ((dd * 128 + k0 * 2) ^ ((dd & 7) << 4))) = vb;
  }
}

// ---------------------------------------------------------------------------
// Main: 128 threads = 2 waves; each wave owns 32 q-rows (2 sub-tiles of 16).
// Double-buffered K/V images staged via global_load_lds; ONE barrier per iter.
// ---------------------------------------------------------------------------
__global__ __launch_bounds__(128, 2) void attn_main(
    const float* __restrict__ Q, const char* __restrict__ img,
    float* __restrict__ O)
{
  __shared__ __align__(16) char buf[2][TILE_BYTES];  // {K 8KB, V 8KB} x dbuf
  __shared__ __align__(16) char Pl[2][4096];         // per-wave P (2 subtiles x 2KB)

  const int tid  = threadIdx.x;
  const int wid  = tid >> 6;
  const int lane = tid & 63;
  const int g    = lane >> 4;
  const int ln   = lane & 15;

  // XCD-chunked bijective block swizzle: 1024 blocks, 128 per XCD -> 2 heads/XCD
  const int bid = blockIdx.x;
  const int wg  = (bid & 7) * 128 + (bid >> 3);
  const int h   = wg >> 6;
  const int qb  = wg & 63;
  const int q0w = qb * 64 + wid * 32;   // this wave's first q row

  const float SCL = 0.125f * 1.4426950408889634f;  // scale * log2(e), folded into Q

  // Q fragments, 2 sub-tiles: lane holds Q[q0w+u*16+ln][g*8..], [32+g*8..]
  short8 qf[2][2];
  #pragma unroll
  for (int u = 0; u < 2; ++u) {
    const float* qp = Q + (size_t)(q0w + u * 16 + ln) * HS + h * D + g * 8;
    qf[u][0] = pack8(*(const f32x4*)(qp),      *(const f32x4*)(qp + 4),  SCL);
    qf[u][1] = pack8(*(const f32x4*)(qp + 32), *(const f32x4*)(qp + 36), SCL);
  }

  float m_run[2] = {-1e30f, -1e30f}, l_run[2] = {0.0f, 0.0f};
  f32x4 oacc[2][4] = {};   // [u][dt]: lane holds O[q=u*16+4g+r][d=dt*16+ln]

  const char* himg = img + (size_t)(h * NT) * TILE_BYTES;

  // stage tile t into buf[b]: 16 chunks of 1KB, 8 per wave
  auto stage = [&](int b, int t) {
    const char* src = himg + (size_t)t * TILE_BYTES + lane * 16;
    char* dst = buf[b];
    #pragma unroll
    for (int i = 0; i < 8; ++i) {
      const int c = wid * 8 + i;
      gload16(src + c * 1024, dst + c * 1024);
    }
  };

  stage(0, 0);
  __syncthreads();                     // drains vmcnt -> buf0 ready
  int cur = 0;

  for (int t = 0; t < NT; ++t) {
    if (t + 1 < NT) stage(cur ^ 1, t + 1);   // prefetch next tile (async)

    const char* Kb = buf[cur];
    const char* Vb = buf[cur] + 8192;

    // ---- QK^T (swapped): sv[u][kt][r] = z[q=u*16+ln][key=kt*16+4g+r] ----
    f32x4 sv[2][4];
    #pragma unroll
    for (int kt = 0; kt < 4; ++kt) {
      const int key = kt * 16 + ln;
      const int sw  = (key & 7) << 4;
      short8 kf0 = *(const short8*)(Kb + ((key * 128 + g * 16) ^ sw));
      short8 kf1 = *(const short8*)(Kb + ((key * 128 + 64 + g * 16) ^ sw));
      #pragma unroll
      for (int u = 0; u < 2; ++u) {
        f32x4 acc = {};
        acc = MFMA16(kf0, qf[u][0], acc);
        acc = MFMA16(kf1, qf[u][1], acc);
        sv[u][kt] = acc;
      }
    }

    // ---- online softmax per sub-tile (exp2 domain) + P write (wave-private) ----
    const int psw = (ln & 7) << 4;
    #pragma unroll
    for (int u = 0; u < 2; ++u) {
      char* Pw = Pl[wid] + u * 2048;
      float zmax = -1e30f;
      #pragma unroll
      for (int kt = 0; kt < 4; ++kt)
        #pragma unroll
        for (int r = 0; r < 4; ++r) zmax = fmaxf(zmax, sv[u][kt][r]);
      zmax = fmaxf(zmax, __shfl_xor(zmax, 16));
      zmax = fmaxf(zmax, __shfl_xor(zmax, 32));
      const float m_new = fmaxf(m_run[u], zmax);
      const float alpha = __builtin_amdgcn_exp2f(m_run[u] - m_new);

      float psum = 0.0f;
      #pragma unroll
      for (int kt = 0; kt < 4; ++kt) {
        float p[4];
        #pragma unroll
        for (int r = 0; r < 4; ++r) {
          p[r] = __builtin_amdgcn_exp2f(sv[u][kt][r] - m_new);
          psum += p[r];
        }
        unsigned w0 = (unsigned)f2bf(p[0]) | ((unsigned)f2bf(p[1]) << 16);
        unsigned w1 = (unsigned)f2bf(p[2]) | ((unsigned)f2bf(p[3]) << 16);
        *(unsigned long long*)(Pw + ((ln * 128 + kt * 32 + 8 * g) ^ psw)) =
            (unsigned long long)w0 | ((unsigned long long)w1 << 32);
      }
      psum += __shfl_xor(psum, 16);
      psum += __shfl_xor(psum, 32);
      l_run[u] = l_run[u] * alpha + psum;
      m_run[u] = m_new;

      // rescale oacc with alpha of ITS row (q = 4g+r): lane 4g+r holds it
      #pragma unroll
      for (int r = 0; r < 4; ++r) {
        const float a_q = __shfl(alpha, 4 * g + r);
        #pragma unroll
        for (int dt = 0; dt < 4; ++dt) oacc[u][dt][r] *= a_q;
      }
    }
    // NO barrier: Plds is wave-private; lgkmcnt orders write->read

    // ---- PV: O[q][d] += P[q][k] * V[k][d] ----
    short8 pa0[2], pa1[2];
    #pragma unroll
    for (int u = 0; u < 2; ++u) {
      const char* Pw = Pl[wid] + u * 2048;
      pa0[u] = *(const short8*)(Pw + ((ln * 128 + g * 16) ^ psw));
      pa1[u] = *(const short8*)(Pw + ((ln * 128 + 64 + g * 16) ^ psw));
    }
    #pragma unroll
    for (int dt = 0; dt < 4; ++dt) {
      const int d  = dt * 16 + ln;
      const int sw = (ln & 7) << 4;   // d&7 == ln&7
      short8 vb0 = *(const short8*)(Vb + ((d * 128 + g * 16) ^ sw));
      short8 vb1 = *(const short8*)(Vb + ((d * 128 + 64 + g * 16) ^ sw));
      #pragma unroll
      for (int u = 0; u < 2; ++u) {
        oacc[u][dt] = MFMA16(pa0[u], vb0, oacc[u][dt]);
        oacc[u][dt] = MFMA16(pa1[u], vb1, oacc[u][dt]);
      }
    }

    __syncthreads();   // drains vmcnt(0) (prefetch landed) + all buf reads done
    cur ^= 1;
  }

  // ---- epilogue ----
  #pragma unroll
  for (int u = 0; u < 2; ++u) {
    #pragma unroll
    for (int r = 0; r < 4; ++r) {
      const int q   = 4 * g + r;
      const float lv  = __shfl(l_run[u], q);
      const float inv = 1.0f / lv;
      float* op = O + (size_t)(q0w + u * 16 + q) * HS + h * D + ln;
      #pragma unroll
      for (int dt = 0; dt < 4; ++dt)
        op[dt * 16] = oacc[u][dt][r] * inv;
    }
  }
}

// ---------------------------------------------------------------------------
// Fallback (ws too small): round-3 monolithic kernel, f32 direct staging.
// ---------------------------------------------------------------------------
static constexpr int PST = 72;
__global__ __launch_bounds__(512) void attn_fb(
    const float* __restrict__ Q, const float* __restrict__ Kf,
    const float* __restrict__ Vf, float* __restrict__ O)
{
  __shared__ __align__(16) ushort Klds[64][PST];
  __shared__ __align__(16) ushort Vt[D][PST];
  __shared__ __align__(16) ushort Plds[8][16][PST];

  const int tid  = threadIdx.x;
  const int wid  = tid >> 6;
  const int lane = tid & 63;
  const int g    = lane >> 4;
  const int ln   = lane & 15;
  const int h    = blockIdx.y;
  const int q0   = blockIdx.x * 128 + wid * 16;
  const float SCL = 0.125f * 1.4426950408889634f;

  short8 qf[2];
  {
    const float* qp = Q + (size_t)(q0 + ln) * HS + h * D + g * 8;
    qf[0] = pack8(*(const f32x4*)(qp),      *(const f32x4*)(qp + 4),  SCL);
    qf[1] = pack8(*(const f32x4*)(qp + 32), *(const f32x4*)(qp + 36), SCL);
  }
  float m_run = -1e30f, l_run = 0.0f;
  f32x4 oacc[4] = {};

  for (int t = 0; t < NT; ++t) {
    const int kv0 = t * 64;
    #pragma unroll
    for (int r = 0; r < 2; ++r) {
      const int key = r * 32 + (tid >> 4);
      const int d0  = (tid & 15) * 4;
      f32x4 kq = *(const f32x4*)(Kf + (size_t)(kv0 + key) * HS + h * D + d0);
      u16x4 kb4;
      #pragma unroll
      for (int j = 0; j < 4; ++j) kb4[j] = f2bf(kq[j]);
      *(u16x4*)&Klds[key][d0] = kb4;
      f32x4 vq = *(const f32x4*)(Vf + (size_t)(kv0 + key) * HS + h * D + d0);
      #pragma unroll
      for (int j = 0; j < 4; ++j) Vt[d0 + j][key] = f2bf(vq[j]);
    }
    __syncthreads();

    f32x4 sv[4];
    #pragma unroll
    for (int kt = 0; kt < 4; ++kt) {
      f32x4 acc = {};
      short8 kf0 = *(const short8*)&Klds[kt * 16 + ln][g * 8];
      short8 kf1 = *(const short8*)&Klds[kt * 16 + ln][32 + g * 8];
      acc = MFMA16(kf0, qf[0], acc);
      acc = MFMA16(kf1, qf[1], acc);
      sv[kt] = acc;
    }
    float zmax = -1e30f;
    #pragma unroll
    for (int kt = 0; kt < 4; ++kt)
      #pragma unroll
      for (int r = 0; r < 4; ++r) zmax = fmaxf(zmax, sv[kt][r]);
    zmax = fmaxf(zmax, __shfl_xor(zmax, 16));
    zmax = fmaxf(zmax, __shfl_xor(zmax, 32));
    const float m_new = fmaxf(m_run, zmax);
    const float alpha = __builtin_amdgcn_exp2f(m_run - m_new);
    float psum = 0.0f;
    #pragma unroll
    for (int kt = 0; kt < 4; ++kt) {
      float p[4];
      #pragma unroll
      for (int r = 0; r < 4; ++r) {
        p[r] = __builtin_amdgcn_exp2f(sv[kt][r] - m_new);
        psum += p[r];
      }
      unsigned w0 = (unsigned)f2bf(p[0]) | ((unsigned)f2bf(p[1]) << 16);
      unsigned w1 = (unsigned)f2bf(p[2]) | ((unsigned)f2bf(p[3]) << 16);
      unsigned* dst = (unsigned*)&Plds[wid][ln][kt * 16 + g * 4];
      dst[0] = w0; dst[1] = w1;
    }
    psum += __shfl_xor(psum, 16);
    psum += __shfl_xor(psum, 32);
    l_run = l_run * alpha + psum;
    m_run = m_new;
    #pragma unroll
    for (int r = 0; r < 4; ++r) {
      const float a_q = __shfl(alpha, 4 * g + r);
      #pragma unroll
      for (int dt = 0; dt < 4; ++dt) oacc[dt][r] *= a_q;
    }
    __syncthreads();

    short8 pa0 = *(const short8*)&Plds[wid][ln][g * 8];
    short8 pa1 = *(const short8*)&Plds[wid][ln][32 + g * 8];
    #pragma unroll
    for (int dt = 0; dt < 4; ++dt) {
      short8 vb0 = *(const short8*)&Vt[dt * 16 + ln][g * 8];
      short8 vb1 = *(const short8*)&Vt[dt * 16 + ln][32 + g * 8];
      oacc[dt] = MFMA16(pa0, vb0, oacc[dt]);
      oacc[dt] = MFMA16(pa1, vb1, oacc[dt]);
    }
    __syncthreads();
  }
  #pragma unroll
  for (int r = 0; r < 4; ++r) {
    const int q = 4 * g + r;
    const float lv  = __shfl(l_run, q);
    const float inv = 1.0f / lv;
    float* op = O + (size_t)(q0 + q) * HS + h * D + ln;
    #pragma unroll
    for (int dt = 0; dt < 4; ++dt)
      op[dt * 16] = oacc[dt][r] * inv;
  }
}

extern "C" void kernel_launch(void* const* d_in, const int* in_sizes, int n_in,
                              void* d_out, int out_size, void* d_ws, size_t ws_size,
                              hipStream_t stream) {
  const float* Q = (const float*)d_in[0];
  const float* K = (const float*)d_in[1];
  const float* V = (const float*)d_in[2];
  float* O = (float*)d_out;

  const size_t need = (size_t)H * NT * TILE_BYTES;   // 16 MB of tile images
  if (ws_size >= need) {
    build_imgs<<<dim3(NT, H), dim3(256), 0, stream>>>(K, V, (char*)d_ws);
    attn_main<<<dim3(1024), dim3(128), 0, stream>>>(Q, (const char*)d_ws, O);
  } else {
    attn_fb<<<dim3(32, 16), dim3(512), 0, stream>>>(Q, K, V, O);
  }
}

// Round 6
// 137.459 us; speedup vs baseline: 1.6325x; 1.1275x over previous
//
#include <hip/hip_runtime.h>
#include <hip/hip_bf16.h>

typedef __attribute__((ext_vector_type(8))) short  short8;
typedef __attribute__((ext_vector_type(4))) float  f32x4;
typedef __attribute__((ext_vector_type(4))) ushort u16x4;

#define MFMA16(a,b,c) __builtin_amdgcn_mfma_f32_16x16x32_bf16((a),(b),(c),0,0,0)

static constexpr int S   = 4096;
static constexpr int H   = 16;
static constexpr int D   = 64;
static constexpr int HS  = H * D;     // 1024 f32 per seq position
static constexpr int NT  = S / 64;    // 64 KV tiles of 64 keys
static constexpr int TILE_BYTES = 16384;  // 8KB K-image + 8KB V-image

// RNE float -> bf16 bits (finite inputs only)
__device__ __forceinline__ ushort f2bf(float x) {
  union { float f; unsigned u; } a; a.f = x;
  unsigned r = a.u + 0x7fffu + ((a.u >> 16) & 1u);
  return (ushort)(r >> 16);
}

// packed f32x2 -> bf16x2 in one HW instruction (no builtin on gfx950; T12 recipe)
__device__ __forceinline__ unsigned cvt_pk_bf16(float lo, float hi) {
  unsigned r;
  asm("v_cvt_pk_bf16_f32 %0, %1, %2" : "=v"(r) : "v"(lo), "v"(hi));
  return r;
}

__device__ __forceinline__ short8 pack8(f32x4 a, f32x4 b, float scl) {
  short8 r;
  #pragma unroll
  for (int j = 0; j < 4; ++j) {
    r[j]     = (short)f2bf(a[j] * scl);
    r[4 + j] = (short)f2bf(b[j] * scl);
  }
  return r;
}

// async global->LDS, 16B per lane; LDS dest is wave-uniform base + lane*16
__device__ __forceinline__ void gload16(const void* g, void* l) {
  __builtin_amdgcn_global_load_lds(
      (const __attribute__((address_space(1))) unsigned int*)g,
      (__attribute__((address_space(3))) unsigned int*)l, 16, 0, 0);
}

// ---------------------------------------------------------------------------
// Pre-pass: build per-(h,t) 16KB LDS images in workspace.
//   K-image byte X = (key*128 + d*2) ^ ((key&7)<<4)   holds bf16 K[t*64+key][h][d]
//   V-image byte X = (d*128 + k*2)  ^ ((d&7)<<4)      holds bf16 V[t*64+k][h][d]
// ---------------------------------------------------------------------------
__global__ __launch_bounds__(256) void build_imgs(
    const float* __restrict__ Kf, const float* __restrict__ Vf,
    char* __restrict__ ws)
{
  __shared__ float vt[64][65];   // f32 V tile, padded for transposed reads
  const int tid = threadIdx.x;
  const int t   = blockIdx.x;
  const int h   = blockIdx.y;
  const size_t base_in = (size_t)(t * 64) * HS + h * D;

  #pragma unroll
  for (int i = 0; i < 4; ++i) {           // stage V tile [64 key][64 d] f32
    const int idx = i * 256 + tid;
    const int key = idx >> 4;
    const int c4  = (idx & 15) * 4;
    f32x4 v = *(const f32x4*)(Vf + base_in + (size_t)key * HS + c4);
    *(f32x4*)&vt[key][c4] = v;
  }
  __syncthreads();

  char* Kimg = ws + (size_t)(h * NT + t) * TILE_BYTES;
  char* Vimg = Kimg + 8192;

  #pragma unroll
  for (int i = 0; i < 2; ++i) {
    const int c   = i * 256 + tid;        // chunk id 0..511
    const int key = c >> 3;
    const int d0  = (c & 7) * 8;
    f32x4 a = *(const f32x4*)(Kf + base_in + (size_t)key * HS + d0);
    f32x4 b = *(const f32x4*)(Kf + base_in + (size_t)key * HS + d0 + 4);
    short8 kb = pack8(a, b, 1.0f);
    *(short8*)(Kimg + ((key * 128 + d0 * 2) ^ ((key & 7) << 4))) = kb;
    const int dd = c >> 3;
    const int k0 = (c & 7) * 8;
    short8 vb;
    #pragma unroll
    for (int j = 0; j < 8; ++j) vb[j] = (short)f2bf(vt[k0 + j][dd]);
    *(short8*)(Vimg + ((dd * 128 + k0 * 2) ^ ((dd & 7) << 4))) = vb;
  }
}

// ---------------------------------------------------------------------------
// Main: 128 threads = 2 waves; each wave owns 32 q-rows (2 sub-tiles of 16).
// Double-buffered K/V images staged via global_load_lds; ONE barrier per iter.
// ---------------------------------------------------------------------------
__global__ __launch_bounds__(128, 2) void attn_main(
    const float* __restrict__ Q, const char* __restrict__ img,
    float* __restrict__ O)
{
  __shared__ __align__(16) char buf[2][TILE_BYTES];  // {K 8KB, V 8KB} x dbuf
  __shared__ __align__(16) char Pl[2][4096];         // per-wave P (2 subtiles x 2KB)

  const int tid  = threadIdx.x;
  const int wid  = tid >> 6;
  const int lane = tid & 63;
  const int g    = lane >> 4;
  const int ln   = lane & 15;

  // XCD-chunked bijective block swizzle: 1024 blocks, 128 per XCD -> 2 heads/XCD
  const int bid = blockIdx.x;
  const int wg  = (bid & 7) * 128 + (bid >> 3);
  const int h   = wg >> 6;
  const int qb  = wg & 63;
  const int q0w = qb * 64 + wid * 32;   // this wave's first q row

  const float SCL = 0.125f * 1.4426950408889634f;  // scale * log2(e), folded into Q

  short8 qf[2][2];
  #pragma unroll
  for (int u = 0; u < 2; ++u) {
    const float* qp = Q + (size_t)(q0w + u * 16 + ln) * HS + h * D + g * 8;
    qf[u][0] = pack8(*(const f32x4*)(qp),      *(const f32x4*)(qp + 4),  SCL);
    qf[u][1] = pack8(*(const f32x4*)(qp + 32), *(const f32x4*)(qp + 36), SCL);
  }

  // lane spaces: softmax stats live in "row q = ln" space (QK^T C/D col);
  // oacc[u][dt][r] lives in "row q = 4g+r" space (PV C/D row).
  float m_run[2] = {-1e30f, -1e30f}, l_run[2] = {0.0f, 0.0f};
  f32x4 oacc[2][4] = {};   // [u][dt]: lane holds O[q=u*16+4g+r][d=dt*16+ln]

  const char* himg = img + (size_t)(h * NT) * TILE_BYTES;

  auto stage = [&](int b, int t) {
    const char* src = himg + (size_t)t * TILE_BYTES + lane * 16;
    char* dst = buf[b];
    #pragma unroll
    for (int i = 0; i < 8; ++i) {
      const int c = wid * 8 + i;
      gload16(src + c * 1024, dst + c * 1024);
    }
  };

  stage(0, 0);
  __syncthreads();
  int cur = 0;

  for (int t = 0; t < NT; ++t) {
    if (t + 1 < NT) stage(cur ^ 1, t + 1);   // async prefetch next tile

    const char* Kb = buf[cur];
    const char* Vb = buf[cur] + 8192;

    // ---- QK^T (swapped): sv[u][kt][r] = z[q=u*16+ln][key=kt*16+4g+r] ----
    f32x4 sv[2][4];
    __builtin_amdgcn_s_setprio(1);
    #pragma unroll
    for (int kt = 0; kt < 4; ++kt) {
      const int key = kt * 16 + ln;
      const int sw  = (key & 7) << 4;
      short8 kf0 = *(const short8*)(Kb + ((key * 128 + g * 16) ^ sw));
      short8 kf1 = *(const short8*)(Kb + ((key * 128 + 64 + g * 16) ^ sw));
      #pragma unroll
      for (int u = 0; u < 2; ++u) {
        f32x4 acc = {};
        acc = MFMA16(kf0, qf[u][0], acc);
        acc = MFMA16(kf1, qf[u][1], acc);
        sv[u][kt] = acc;
      }
    }
    __builtin_amdgcn_s_setprio(0);

    // ---- online softmax (exp2 domain; scale folded into Q) ----
    const int psw = (ln & 7) << 4;
    #pragma unroll
    for (int u = 0; u < 2; ++u) {
      char* Pw = Pl[wid] + u * 2048;

      // row max: pairwise + max3-fusable triples
      float mp[8];
      #pragma unroll
      for (int kt = 0; kt < 4; ++kt) {
        mp[kt * 2]     = fmaxf(sv[u][kt][0], sv[u][kt][1]);
        mp[kt * 2 + 1] = fmaxf(sv[u][kt][2], sv[u][kt][3]);
      }
      float t0 = fmaxf(fmaxf(mp[0], mp[1]), mp[2]);
      float t1 = fmaxf(fmaxf(mp[3], mp[4]), mp[5]);
      float t2 = fmaxf(fmaxf(mp[6], mp[7]), t0);
      float zmax = fmaxf(t1, t2);
      zmax = fmaxf(zmax, __shfl_xor(zmax, 16));
      zmax = fmaxf(zmax, __shfl_xor(zmax, 32));

      // defer-max (T13): only rescale when some row grew by > 8 (exp2 domain).
      // Wave-uniform branch (__all) -> no divergence.
      if (!__all(zmax - m_run[u] <= 8.0f)) {
        const float m_new = fmaxf(m_run[u], zmax);
        const float alpha = __builtin_amdgcn_exp2f(m_run[u] - m_new);
        m_run[u] = m_new;
        l_run[u] *= alpha;
        #pragma unroll
        for (int r = 0; r < 4; ++r) {
          const float a_q = __shfl(alpha, 4 * g + r);  // lane 4g+r holds row-(4g+r) alpha
          #pragma unroll
          for (int dt = 0; dt < 4; ++dt) oacc[u][dt][r] *= a_q;
        }
      }
      const float mx = m_run[u];

      float psum = 0.0f;
      #pragma unroll
      for (int kt = 0; kt < 4; ++kt) {
        const float p0 = __builtin_amdgcn_exp2f(sv[u][kt][0] - mx);
        const float p1 = __builtin_amdgcn_exp2f(sv[u][kt][1] - mx);
        const float p2 = __builtin_amdgcn_exp2f(sv[u][kt][2] - mx);
        const float p3 = __builtin_amdgcn_exp2f(sv[u][kt][3] - mx);
        psum += (p0 + p1) + (p2 + p3);
        const unsigned w0 = cvt_pk_bf16(p0, p1);   // v_cvt_pk_bf16_f32
        const unsigned w1 = cvt_pk_bf16(p2, p3);
        *(unsigned long long*)(Pw + ((ln * 128 + kt * 32 + 8 * g) ^ psw)) =
            (unsigned long long)w0 | ((unsigned long long)w1 << 32);
      }
      psum += __shfl_xor(psum, 16);
      psum += __shfl_xor(psum, 32);
      l_run[u] += psum;
    }
    // NO barrier: Plds is wave-private; lgkmcnt orders write->read

    // ---- PV: O[q][d] += P[q][k] * V[k][d] ----
    short8 pa0[2], pa1[2];
    #pragma unroll
    for (int u = 0; u < 2; ++u) {
      const char* Pw = Pl[wid] + u * 2048;
      pa0[u] = *(const short8*)(Pw + ((ln * 128 + g * 16) ^ psw));
      pa1[u] = *(const short8*)(Pw + ((ln * 128 + 64 + g * 16) ^ psw));
    }
    __builtin_amdgcn_s_setprio(1);
    #pragma unroll
    for (int dt = 0; dt < 4; ++dt) {
      const int d  = dt * 16 + ln;
      const int sw = (ln & 7) << 4;   // d&7 == ln&7
      short8 vb0 = *(const short8*)(Vb + ((d * 128 + g * 16) ^ sw));
      short8 vb1 = *(const short8*)(Vb + ((d * 128 + 64 + g * 16) ^ sw));
      #pragma unroll
      for (int u = 0; u < 2; ++u) {
        oacc[u][dt] = MFMA16(pa0[u], vb0, oacc[u][dt]);
        oacc[u][dt] = MFMA16(pa1[u], vb1, oacc[u][dt]);
      }
    }
    __builtin_amdgcn_s_setprio(0);

    __syncthreads();   // drains vmcnt (prefetch landed) + all buf reads done
    cur ^= 1;
  }

  // ---- epilogue ----
  #pragma unroll
  for (int u = 0; u < 2; ++u) {
    #pragma unroll
    for (int r = 0; r < 4; ++r) {
      const int q   = 4 * g + r;
      const float lv  = __shfl(l_run[u], q);
      const float inv = 1.0f / lv;
      float* op = O + (size_t)(q0w + u * 16 + q) * HS + h * D + ln;
      #pragma unroll
      for (int dt = 0; dt < 4; ++dt)
        op[dt * 16] = oacc[u][dt][r] * inv;
    }
  }
}

// ---------------------------------------------------------------------------
// Fallback (ws too small): round-3 monolithic kernel, f32 direct staging.
// ---------------------------------------------------------------------------
static constexpr int PST = 72;
__global__ __launch_bounds__(512) void attn_fb(
    const float* __restrict__ Q, const float* __restrict__ Kf,
    const float* __restrict__ Vf, float* __restrict__ O)
{
  __shared__ __align__(16) ushort Klds[64][PST];
  __shared__ __align__(16) ushort Vt[D][PST];
  __shared__ __align__(16) ushort Plds[8][16][PST];

  const int tid  = threadIdx.x;
  const int wid  = tid >> 6;
  const int lane = tid & 63;
  const int g    = lane >> 4;
  const int ln   = lane & 15;
  const int h    = blockIdx.y;
  const int q0   = blockIdx.x * 128 + wid * 16;
  const float SCL = 0.125f * 1.4426950408889634f;

  short8 qf[2];
  {
    const float* qp = Q + (size_t)(q0 + ln) * HS + h * D + g * 8;
    qf[0] = pack8(*(const f32x4*)(qp),      *(const f32x4*)(qp + 4),  SCL);
    qf[1] = pack8(*(const f32x4*)(qp + 32), *(const f32x4*)(qp + 36), SCL);
  }
  float m_run = -1e30f, l_run = 0.0f;
  f32x4 oacc[4] = {};

  for (int t = 0; t < NT; ++t) {
    const int kv0 = t * 64;
    #pragma unroll
    for (int r = 0; r < 2; ++r) {
      const int key = r * 32 + (tid >> 4);
      const int d0  = (tid & 15) * 4;
      f32x4 kq = *(const f32x4*)(Kf + (size_t)(kv0 + key) * HS + h * D + d0);
      u16x4 kb4;
      #pragma unroll
      for (int j = 0; j < 4; ++j) kb4[j] = f2bf(kq[j]);
      *(u16x4*)&Klds[key][d0] = kb4;
      f32x4 vq = *(const f32x4*)(Vf + (size_t)(kv0 + key) * HS + h * D + d0);
      #pragma unroll
      for (int j = 0; j < 4; ++j) Vt[d0 + j][key] = f2bf(vq[j]);
    }
    __syncthreads();

    f32x4 sv[4];
    #pragma unroll
    for (int kt = 0; kt < 4; ++kt) {
      f32x4 acc = {};
      short8 kf0 = *(const short8*)&Klds[kt * 16 + ln][g * 8];
      short8 kf1 = *(const short8*)&Klds[kt * 16 + ln][32 + g * 8];
      acc = MFMA16(kf0, qf[0], acc);
      acc = MFMA16(kf1, qf[1], acc);
      sv[kt] = acc;
    }
    float zmax = -1e30f;
    #pragma unroll
    for (int kt = 0; kt < 4; ++kt)
      #pragma unroll
      for (int r = 0; r < 4; ++r) zmax = fmaxf(zmax, sv[kt][r]);
    zmax = fmaxf(zmax, __shfl_xor(zmax, 16));
    zmax = fmaxf(zmax, __shfl_xor(zmax, 32));
    const float m_new = fmaxf(m_run, zmax);
    const float alpha = __builtin_amdgcn_exp2f(m_run - m_new);
    float psum = 0.0f;
    #pragma unroll
    for (int kt = 0; kt < 4; ++kt) {
      float p[4];
      #pragma unroll
      for (int r = 0; r < 4; ++r) {
        p[r] = __builtin_amdgcn_exp2f(sv[kt][r] - m_new);
        psum += p[r];
      }
      unsigned w0 = (unsigned)f2bf(p[0]) | ((unsigned)f2bf(p[1]) << 16);
      unsigned w1 = (unsigned)f2bf(p[2]) | ((unsigned)f2bf(p[3]) << 16);
      unsigned* dst = (unsigned*)&Plds[wid][ln][kt * 16 + g * 4];
      dst[0] = w0; dst[1] = w1;
    }
    psum += __shfl_xor(psum, 16);
    psum += __shfl_xor(psum, 32);
    l_run = l_run * alpha + psum;
    m_run = m_new;
    #pragma unroll
    for (int r = 0; r < 4; ++r) {
      const float a_q = __shfl(alpha, 4 * g + r);
      #pragma unroll
      for (int dt = 0; dt < 4; ++dt) oacc[dt][r] *= a_q;
    }
    __syncthreads();

    short8 pa0 = *(const short8*)&Plds[wid][ln][g * 8];
    short8 pa1 = *(const short8*)&Plds[wid][ln][32 + g * 8];
    #pragma unroll
    for (int dt = 0; dt < 4; ++dt) {
      short8 vb0 = *(const short8*)&Vt[dt * 16 + ln][g * 8];
      short8 vb1 = *(const short8*)&Vt[dt * 16 + ln][32 + g * 8];
      oacc[dt] = MFMA16(pa0, vb0, oacc[dt]);
      oacc[dt] = MFMA16(pa1, vb1, oacc[dt]);
    }
    __syncthreads();
  }
  #pragma unroll
  for (int r = 0; r < 4; ++r) {
    const int q = 4 * g + r;
    const float lv  = __shfl(l_run, q);
    const float inv = 1.0f / lv;
    float* op = O + (size_t)(q0 + q) * HS + h * D + ln;
    #pragma unroll
    for (int dt = 0; dt < 4; ++dt)
      op[dt * 16] = oacc[dt][r] * inv;
  }
}

extern "C" void kernel_launch(void* const* d_in, const int* in_sizes, int n_in,
                              void* d_out, int out_size, void* d_ws, size_t ws_size,
                              hipStream_t stream) {
  const float* Q = (const float*)d_in[0];
  const float* K = (const float*)d_in[1];
  const float* V = (const float*)d_in[2];
  float* O = (float*)d_out;

  const size_t need = (size_t)H * NT * TILE_BYTES;   // 16 MB of tile images
  if (ws_size >= need) {
    build_imgs<<<dim3(NT, H), dim3(256), 0, stream>>>(K, V, (char*)d_ws);
    attn_main<<<dim3(1024), dim3(128), 0, stream>>>(Q, (const char*)d_ws, O);
  } else {
    attn_fb<<<dim3(32, 16), dim3(512), 0, stream>>>(Q, K, V, O);
  }
}

// Round 7
// 127.548 us; speedup vs baseline: 1.7594x; 1.0777x over previous
//
#include <hip/hip_runtime.h>
#include <hip/hip_bf16.h>

typedef __attribute__((ext_vector_type(8)))  short  short8;
typedef __attribute__((ext_vector_type(4)))  float  f32x4;
typedef __attribute__((ext_vector_type(16))) float  f32x16;
typedef __attribute__((ext_vector_type(4)))  ushort u16x4;

#define MFMA16(a,b,c) __builtin_amdgcn_mfma_f32_16x16x32_bf16((a),(b),(c),0,0,0)
#define MFMA32(a,b,c) __builtin_amdgcn_mfma_f32_32x32x16_bf16((a),(b),(c),0,0,0)

static constexpr int S   = 4096;
static constexpr int H   = 16;
static constexpr int D   = 64;
static constexpr int HS  = H * D;     // 1024 f32 per seq position
static constexpr int NT  = S / 64;    // 64 KV tiles of 64 keys
static constexpr int TILE_BYTES = 16384;  // 8KB K-image + 8KB V-image

// RNE float -> bf16 bits (finite inputs only)
__device__ __forceinline__ ushort f2bf(float x) {
  union { float f; unsigned u; } a; a.f = x;
  unsigned r = a.u + 0x7fffu + ((a.u >> 16) & 1u);
  return (ushort)(r >> 16);
}

// packed f32x2 -> bf16x2 in one HW instruction
__device__ __forceinline__ unsigned cvt_pk_bf16(float lo, float hi) {
  unsigned r;
  asm("v_cvt_pk_bf16_f32 %0, %1, %2" : "=v"(r) : "v"(lo), "v"(hi));
  return r;
}

__device__ __forceinline__ short8 pack8(f32x4 a, f32x4 b, float scl) {
  short8 r;
  #pragma unroll
  for (int j = 0; j < 4; ++j) {
    r[j]     = (short)f2bf(a[j] * scl);
    r[4 + j] = (short)f2bf(b[j] * scl);
  }
  return r;
}

// async global->LDS, 16B per lane; LDS dest is wave-uniform base + lane*16
__device__ __forceinline__ void gload16(const void* g, void* l) {
  __builtin_amdgcn_global_load_lds(
      (const __attribute__((address_space(1))) unsigned int*)g,
      (__attribute__((address_space(3))) unsigned int*)l, 16, 0, 0);
}

// ---------------------------------------------------------------------------
// Pre-pass: build per-(h,t) 16KB LDS images in workspace.
//   K-image byte X = (key*128 + d*2) ^ ((key&7)<<4)   holds bf16 K[t*64+key][h][d]
//   V-image byte X = (d*128 + k*2)  ^ ((d&7)<<4)      holds bf16 V[t*64+k][h][d]
// ---------------------------------------------------------------------------
__global__ __launch_bounds__(256) void build_imgs(
    const float* __restrict__ Kf, const float* __restrict__ Vf,
    char* __restrict__ ws)
{
  __shared__ float vt[64][65];   // f32 V tile, padded for transposed reads
  const int tid = threadIdx.x;
  const int t   = blockIdx.x;
  const int h   = blockIdx.y;
  const size_t base_in = (size_t)(t * 64) * HS + h * D;

  #pragma unroll
  for (int i = 0; i < 4; ++i) {           // stage V tile [64 key][64 d] f32
    const int idx = i * 256 + tid;
    const int key = idx >> 4;
    const int c4  = (idx & 15) * 4;
    f32x4 v = *(const f32x4*)(Vf + base_in + (size_t)key * HS + c4);
    *(f32x4*)&vt[key][c4] = v;
  }
  __syncthreads();

  char* Kimg = ws + (size_t)(h * NT + t) * TILE_BYTES;
  char* Vimg = Kimg + 8192;

  #pragma unroll
  for (int i = 0; i < 2; ++i) {
    const int c   = i * 256 + tid;        // chunk id 0..511
    const int key = c >> 3;
    const int d0  = (c & 7) * 8;
    f32x4 a = *(const f32x4*)(Kf + base_in + (size_t)key * HS + d0);
    f32x4 b = *(const f32x4*)(Kf + base_in + (size_t)key * HS + d0 + 4);
    short8 kb = pack8(a, b, 1.0f);
    *(short8*)(Kimg + ((key * 128 + d0 * 2) ^ ((key & 7) << 4))) = kb;
    const int dd = c >> 3;
    const int k0 = (c & 7) * 8;
    short8 vb;
    #pragma unroll
    for (int j = 0; j < 8; ++j) vb[j] = (short)f2bf(vt[k0 + j][dd]);
    *(short8*)(Vimg + ((dd * 128 + k0 * 2) ^ ((dd & 7) << 4))) = vb;
  }
}

// ---------------------------------------------------------------------------
// Main: 128 threads = 2 waves; each wave owns 32 q-rows via ONE 32x32 MFMA col.
// Swapped QK^T (A=K, B=Q) -> C[key][q], q = lane&31: softmax stats, rescale and
// PV output all share the q=lane&31 lane space. P stays in registers:
// cvt_pk_bf16 + permlane32_swap builds PV B-fragments directly (T12).
//
// 32x32x16 layouts used (A/B by analogy with verified 16x16x32; C/D per m74):
//   A[row=l&31][k = 8*(l>>5)+j]   B[k = 8*(l>>5)+j][col = l&31]
//   C/D: col = l&31, row = (reg&3) + 8*(reg>>2) + 4*(l>>5)
// ---------------------------------------------------------------------------
__global__ __launch_bounds__(128, 2) void attn_main(
    const float* __restrict__ Q, const char* __restrict__ img,
    float* __restrict__ O)
{
  __shared__ __align__(16) char buf[2][TILE_BYTES];  // {K 8KB, V 8KB} x dbuf

  const int tid  = threadIdx.x;
  const int wid  = tid >> 6;
  const int lane = tid & 63;
  const int q    = lane & 31;   // this lane's softmax row
  const int hl   = lane >> 5;   // half-wave (k-group) id

  // XCD-chunked bijective block swizzle: 1024 blocks, 128 per XCD -> 2 heads/XCD
  const int bid = blockIdx.x;
  const int wg  = (bid & 7) * 128 + (bid >> 3);
  const int h   = wg >> 6;
  const int qb  = wg & 63;
  const int q0w = qb * 64 + wid * 32;   // this wave's first q row

  const float SCL = 0.125f * 1.4426950408889634f;  // scale * log2(e), folded into Q

  // Q fragments (B-operand): qf[s] holds Q[q0w+q][s*16 + 8*hl + 0..7]
  short8 qf[4];
  {
    const float* qp = Q + (size_t)(q0w + q) * HS + h * D + 8 * hl;
    #pragma unroll
    for (int s = 0; s < 4; ++s)
      qf[s] = pack8(*(const f32x4*)(qp + s * 16), *(const f32x4*)(qp + s * 16 + 4), SCL);
  }

  float m_run = -1e30f, l_run = 0.0f;       // for row q = lane&31 (dup'd across halves)
  f32x16 oacc[2] = {};                      // C[d = krow(reg,l)+32*db][q = lane&31]

  const char* himg = img + (size_t)(h * NT) * TILE_BYTES;

  auto stage = [&](int b, int t) {
    const char* src = himg + (size_t)t * TILE_BYTES + lane * 16;
    char* dst = buf[b];
    #pragma unroll
    for (int i = 0; i < 8; ++i) {
      const int c = wid * 8 + i;
      gload16(src + c * 1024, dst + c * 1024);
    }
  };

  stage(0, 0);
  __syncthreads();
  int cur = 0;

  const int ksw = (q & 7) << 4;   // K/V image row swizzle (key&7 == d&7 == q&7 here)

  for (int t = 0; t < NT; ++t) {
    if (t + 1 < NT) stage(cur ^ 1, t + 1);   // async prefetch next tile

    const char* Kb = buf[cur];
    const char* Vb = buf[cur] + 8192;

    // ---- QK^T: sv[kb] = C[key = kb*32 + krow][q] ----
    f32x16 sv0 = {}, sv1 = {};
    __builtin_amdgcn_s_setprio(1);
    #pragma unroll
    for (int s = 0; s < 4; ++s) {
      const int cb = s * 32 + 16 * hl;                 // d-offset bytes
      short8 kf0 = *(const short8*)(Kb + ((q * 128 + cb) ^ ksw));          // keys 0..31
      short8 kf1 = *(const short8*)(Kb + (((q + 32) * 128 + cb) ^ ksw));   // keys 32..63
      sv0 = MFMA32(kf0, qf[s], sv0);
      sv1 = MFMA32(kf1, qf[s], sv1);
    }
    __builtin_amdgcn_s_setprio(0);

    // ---- lane-local online softmax (exp2 domain; scale folded into Q) ----
    float zA0 = fmaxf(sv0[0], sv1[0]);
    float zA1 = fmaxf(sv0[1], sv1[1]);
    float zA2 = fmaxf(sv0[2], sv1[2]);
    float zA3 = fmaxf(sv0[3], sv1[3]);
    #pragma unroll
    for (int r = 4; r < 16; r += 4) {
      zA0 = fmaxf(zA0, fmaxf(sv0[r],     sv1[r]));
      zA1 = fmaxf(zA1, fmaxf(sv0[r + 1], sv1[r + 1]));
      zA2 = fmaxf(zA2, fmaxf(sv0[r + 2], sv1[r + 2]));
      zA3 = fmaxf(zA3, fmaxf(sv0[r + 3], sv1[r + 3]));
    }
    float zmax = fmaxf(fmaxf(zA0, zA1), fmaxf(zA2, zA3));
    zmax = fmaxf(zmax, __shfl_xor(zmax, 32));   // other 32 keys live in lane^32

    // defer-max (T13): rescale only when some row grew by > 8 (exp2 domain)
    if (!__all(zmax - m_run <= 8.0f)) {
      const float m_new = fmaxf(m_run, zmax);
      const float alpha = __builtin_amdgcn_exp2f(m_run - m_new);
      m_run = m_new;
      l_run *= alpha;
      #pragma unroll
      for (int r = 0; r < 16; ++r) { oacc[0][r] *= alpha; oacc[1][r] *= alpha; }
    }
    const float mx = m_run;

    // exp2 + packed bf16; quad a of sv[kb] covers keys kb*32 + 8a + {0..3} (+4 hi)
    unsigned c01[2][4], c23[2][4];
    float ps0 = 0.f, ps1 = 0.f, ps2 = 0.f, ps3 = 0.f;
    #pragma unroll
    for (int a = 0; a < 4; ++a) {
      float p0 = __builtin_amdgcn_exp2f(sv0[4 * a]     - mx);
      float p1 = __builtin_amdgcn_exp2f(sv0[4 * a + 1] - mx);
      float p2 = __builtin_amdgcn_exp2f(sv0[4 * a + 2] - mx);
      float p3 = __builtin_amdgcn_exp2f(sv0[4 * a + 3] - mx);
      ps0 += p0; ps1 += p1; ps2 += p2; ps3 += p3;
      c01[0][a] = cvt_pk_bf16(p0, p1);
      c23[0][a] = cvt_pk_bf16(p2, p3);
      p0 = __builtin_amdgcn_exp2f(sv1[4 * a]     - mx);
      p1 = __builtin_amdgcn_exp2f(sv1[4 * a + 1] - mx);
      p2 = __builtin_amdgcn_exp2f(sv1[4 * a + 2] - mx);
      p3 = __builtin_amdgcn_exp2f(sv1[4 * a + 3] - mx);
      ps0 += p0; ps1 += p1; ps2 += p2; ps3 += p3;
      c01[1][a] = cvt_pk_bf16(p0, p1);
      c23[1][a] = cvt_pk_bf16(p2, p3);
    }
    float psum = (ps0 + ps1) + (ps2 + ps3);
    psum += __shfl_xor(psum, 32);
    l_run += psum;

    // ---- build PV B-frags in-register via permlane32_swap ----
    // B-frag(step = kb*2+su): keys kb*32+su*16+{0..7} (lo lanes) / {8..15} (hi).
    // swap(c[2su], c[2su+1]) -> vdst = word for j-pair low half, vsrc = high half,
    // valid for BOTH lane halves simultaneously (one swap fills two words).
    short8 pb[4];
    #pragma unroll
    for (int kb = 0; kb < 2; ++kb) {
      #pragma unroll
      for (int su = 0; su < 2; ++su) {
        unsigned w01a = c01[kb][2 * su], w01b = c01[kb][2 * su + 1];
        unsigned w23a = c23[kb][2 * su], w23b = c23[kb][2 * su + 1];
        asm("v_permlane32_swap_b32 %0, %1" : "+v"(w01a), "+v"(w01b));
        asm("v_permlane32_swap_b32 %0, %1" : "+v"(w23a), "+v"(w23b));
        union { short8 s; unsigned u[4]; } f;
        f.u[0] = w01a; f.u[1] = w23a; f.u[2] = w01b; f.u[3] = w23b;
        pb[kb * 2 + su] = f.s;
      }
    }

    // ---- PV: C[d][q] += V^T[d][key] * P[key][q] ----
    __builtin_amdgcn_s_setprio(1);
    #pragma unroll
    for (int st = 0; st < 4; ++st) {
      const int kcb = st * 32 + 16 * hl;               // key-offset bytes
      short8 va0 = *(const short8*)(Vb + ((q * 128 + kcb) ^ ksw));          // d 0..31
      short8 va1 = *(const short8*)(Vb + (((q + 32) * 128 + kcb) ^ ksw));   // d 32..63
      oacc[0] = MFMA32(va0, pb[st], oacc[0]);
      oacc[1] = MFMA32(va1, pb[st], oacc[1]);
    }
    __builtin_amdgcn_s_setprio(0);

    __syncthreads();   // drains vmcnt (prefetch landed) + all buf reads done
    cur ^= 1;
  }

  // ---- epilogue: divide by row sum, store f32 ----
  const float inv = 1.0f / l_run;
  float* op = O + (size_t)(q0w + q) * HS + h * D;
  #pragma unroll
  for (int db = 0; db < 2; ++db) {
    #pragma unroll
    for (int r = 0; r < 16; ++r) {
      const int d = (r & 3) + 8 * (r >> 2) + 4 * hl + 32 * db;
      op[d] = oacc[db][r] * inv;
    }
  }
}

// ---------------------------------------------------------------------------
// Fallback (ws too small): round-3 monolithic kernel, f32 direct staging.
// ---------------------------------------------------------------------------
static constexpr int PST = 72;
__global__ __launch_bounds__(512) void attn_fb(
    const float* __restrict__ Q, const float* __restrict__ Kf,
    const float* __restrict__ Vf, float* __restrict__ O)
{
  __shared__ __align__(16) ushort Klds[64][PST];
  __shared__ __align__(16) ushort Vt[D][PST];
  __shared__ __align__(16) ushort Plds[8][16][PST];

  const int tid  = threadIdx.x;
  const int wid  = tid >> 6;
  const int lane = tid & 63;
  const int g    = lane >> 4;
  const int ln   = lane & 15;
  const int h    = blockIdx.y;
  const int q0   = blockIdx.x * 128 + wid * 16;
  const float SCL = 0.125f * 1.4426950408889634f;

  short8 qf[2];
  {
    const float* qp = Q + (size_t)(q0 + ln) * HS + h * D + g * 8;
    qf[0] = pack8(*(const f32x4*)(qp),      *(const f32x4*)(qp + 4),  SCL);
    qf[1] = pack8(*(const f32x4*)(qp + 32), *(const f32x4*)(qp + 36), SCL);
  }
  float m_run = -1e30f, l_run = 0.0f;
  f32x4 oacc[4] = {};

  for (int t = 0; t < NT; ++t) {
    const int kv0 = t * 64;
    #pragma unroll
    for (int r = 0; r < 2; ++r) {
      const int key = r * 32 + (tid >> 4);
      const int d0  = (tid & 15) * 4;
      f32x4 kq = *(const f32x4*)(Kf + (size_t)(kv0 + key) * HS + h * D + d0);
      u16x4 kb4;
      #pragma unroll
      for (int j = 0; j < 4; ++j) kb4[j] = f2bf(kq[j]);
      *(u16x4*)&Klds[key][d0] = kb4;
      f32x4 vq = *(const f32x4*)(Vf + (size_t)(kv0 + key) * HS + h * D + d0);
      #pragma unroll
      for (int j = 0; j < 4; ++j) Vt[d0 + j][key] = f2bf(vq[j]);
    }
    __syncthreads();

    f32x4 sv[4];
    #pragma unroll
    for (int kt = 0; kt < 4; ++kt) {
      f32x4 acc = {};
      short8 kf0 = *(const short8*)&Klds[kt * 16 + ln][g * 8];
      short8 kf1 = *(const short8*)&Klds[kt * 16 + ln][32 + g * 8];
      acc = MFMA16(kf0, qf[0], acc);
      acc = MFMA16(kf1, qf[1], acc);
      sv[kt] = acc;
    }
    float zmax = -1e30f;
    #pragma unroll
    for (int kt = 0; kt < 4; ++kt)
      #pragma unroll
      for (int r = 0; r < 4; ++r) zmax = fmaxf(zmax, sv[kt][r]);
    zmax = fmaxf(zmax, __shfl_xor(zmax, 16));
    zmax = fmaxf(zmax, __shfl_xor(zmax, 32));
    const float m_new = fmaxf(m_run, zmax);
    const float alpha = __builtin_amdgcn_exp2f(m_run - m_new);
    float psum = 0.0f;
    #pragma unroll
    for (int kt = 0; kt < 4; ++kt) {
      float p[4];
      #pragma unroll
      for (int r = 0; r < 4; ++r) {
        p[r] = __builtin_amdgcn_exp2f(sv[kt][r] - m_new);
        psum += p[r];
      }
      unsigned w0 = (unsigned)f2bf(p[0]) | ((unsigned)f2bf(p[1]) << 16);
      unsigned w1 = (unsigned)f2bf(p[2]) | ((unsigned)f2bf(p[3]) << 16);
      unsigned* dst = (unsigned*)&Plds[wid][ln][kt * 16 + g * 4];
      dst[0] = w0; dst[1] = w1;
    }
    psum += __shfl_xor(psum, 16);
    psum += __shfl_xor(psum, 32);
    l_run = l_run * alpha + psum;
    m_run = m_new;
    #pragma unroll
    for (int r = 0; r < 4; ++r) {
      const float a_q = __shfl(alpha, 4 * g + r);
      #pragma unroll
      for (int dt = 0; dt < 4; ++dt) oacc[dt][r] *= a_q;
    }
    __syncthreads();

    short8 pa0 = *(const short8*)&Plds[wid][ln][g * 8];
    short8 pa1 = *(const short8*)&Plds[wid][ln][32 + g * 8];
    #pragma unroll
    for (int dt = 0; dt < 4; ++dt) {
      short8 vb0 = *(const short8*)&Vt[dt * 16 + ln][g * 8];
      short8 vb1 = *(const short8*)&Vt[dt * 16 + ln][32 + g * 8];
      oacc[dt] = MFMA16(pa0, vb0, oacc[dt]);
      oacc[dt] = MFMA16(pa1, vb1, oacc[dt]);
    }
    __syncthreads();
  }
  #pragma unroll
  for (int r = 0; r < 4; ++r) {
    const int q = 4 * g + r;
    const float lv  = __shfl(l_run, q);
    const float inv = 1.0f / lv;
    float* op = O + (size_t)(q0 + q) * HS + h * D + ln;
    #pragma unroll
    for (int dt = 0; dt < 4; ++dt)
      op[dt * 16] = oacc[dt][r] * inv;
  }
}

extern "C" void kernel_launch(void* const* d_in, const int* in_sizes, int n_in,
                              void* d_out, int out_size, void* d_ws, size_t ws_size,
                              hipStream_t stream) {
  const float* Q = (const float*)d_in[0];
  const float* K = (const float*)d_in[1];
  const float* V = (const float*)d_in[2];
  float* O = (float*)d_out;

  const size_t need = (size_t)H * NT * TILE_BYTES;   // 16 MB of tile images
  if (ws_size >= need) {
    build_imgs<<<dim3(NT, H), dim3(256), 0, stream>>>(K, V, (char*)d_ws);
    attn_main<<<dim3(1024), dim3(128), 0, stream>>>(Q, (const char*)d_ws, O);
  } else {
    attn_fb<<<dim3(32, 16), dim3(512), 0, stream>>>(Q, K, V, O);
  }
}